// Round 4
// baseline (973.840 us; speedup 1.0000x reference)
//
#include <hip/hip_runtime.h>

typedef unsigned short u16;
typedef unsigned int u32;
typedef __attribute__((ext_vector_type(8))) short bf16x8;
typedef __attribute__((ext_vector_type(8))) u16 u16x8;
typedef __attribute__((ext_vector_type(4))) u16 u16x4;
typedef __attribute__((ext_vector_type(4))) u32 u32x4;
typedef __attribute__((ext_vector_type(4))) float f32x4;

#define DEV static __device__ __forceinline__

DEV u16 f2bf(float f) {
    union { float f; u32 u; } v; v.f = f;
    u32 r = v.u + 0x7FFFu + ((v.u >> 16) & 1u);
    return (u16)(r >> 16);
}

DEV u32 cvtpk(float lo, float hi) {
    u32 r;
    asm("v_cvt_pk_bf16_f32 %0, %1, %2" : "=v"(r) : "v"(lo), "v"(hi));
    return r;
}

DEV int swzc(int r, int c) { return c ^ ((r >> 1) & 3); }

DEV void gload_lds16(const void* g, void* l) {
    __builtin_amdgcn_global_load_lds((const __attribute__((address_space(1))) void*)g,
                                     (__attribute__((address_space(3))) void*)l, 16, 0, 0);
}

// ---------------------------------------------------------------------------
// Streaming big-pass GEMM: C_part[s][M][N] = A[M][K] @ Bt[N][K]^T, N = WAVES*64.
// NO LDS, NO BARRIERS: A and B MFMA fragments loaded global->VGPR (16B/lane,
// 16 rows x 64B per fragment = perfectly coalesced). B panel is L1/L2-hot
// (reused by all row-blocks); A is the HBM stream. 2-deep register pipeline
// with named buffers (static indexing only). Wave tile 64x64, FI=FJ=4.
// AF32: A is fp32 -> cvt_pk to bf16 at use. DUMPA: wave 0 writes bf16 A copy.
// ---------------------------------------------------------------------------
template<int WAVES, int MINW, bool AF32, bool DUMPA>
__global__ __launch_bounds__(WAVES * 64, MINW) void pstream_k(
    const void* __restrict__ Ap, const u16* __restrict__ Bt,
    float* __restrict__ Cp, u16* __restrict__ Adump,
    int M, int K, int lda, int ldb, int nRT, int KCH, int cpx)
{
    constexpr int NOUT = WAVES * 64;
    const int tid = threadIdx.x;
    int bid0 = blockIdx.x;
    int bid = (bid0 & 7) * cpx + (bid0 >> 3);       // XCD-contiguous (grid % 8 == 0)
    const int rt = bid % nRT;
    const int s  = bid / nRT;
    const int m0 = rt * 64;
    const int kBeg = s * KCH;
    const int kEnd = (K < kBeg + KCH) ? K : (kBeg + KCH);
    const int nsteps = (kEnd - kBeg) >> 5;

    const int wv = tid >> 6, l = tid & 63;
    const int wn = wv * 64;
    const int lr = l & 15, lg = l >> 4;

    int aoff[4], boff[4], arow[4];
    #pragma unroll
    for (int i = 0; i < 4; i++) {
        int gm = m0 + i * 16 + lr; arow[i] = gm;
        if (gm > M - 1) gm = M - 1;
        aoff[i] = gm * lda + lg * 8;
    }
    #pragma unroll
    for (int j = 0; j < 4; j++) boff[j] = (wn + j * 16 + lr) * ldb + lg * 8;

    f32x4 acc[4][4] = {};
    const u16* Ab = (const u16*)Ap;
    const float* Af = (const float*)Ap;

    bf16x8 a0[4], a1[4], b0[4], b1[4];
    float4 r0[4][2], r1[4][2];

    auto loadB = [&](bf16x8 (&bf)[4], int k) {
        #pragma unroll
        for (int j = 0; j < 4; j++)
            bf[j] = *(const bf16x8*)(Bt + (size_t)k + boff[j]);
    };
    auto loadA16 = [&](bf16x8 (&af)[4], int k) {
        #pragma unroll
        for (int i = 0; i < 4; i++)
            af[i] = *(const bf16x8*)(Ab + (size_t)k + aoff[i]);
    };
    auto loadA32 = [&](float4 (&raw)[4][2], int k) {
        #pragma unroll
        for (int i = 0; i < 4; i++) {
            const float4* p = (const float4*)(Af + (size_t)k + aoff[i]);
            raw[i][0] = p[0]; raw[i][1] = p[1];
        }
    };
    auto cvtA = [&](float4 (&raw)[4][2], bf16x8 (&af)[4], int k) {
        #pragma unroll
        for (int i = 0; i < 4; i++) {
            u32x4 pk;
            pk[0] = cvtpk(raw[i][0].x, raw[i][0].y);
            pk[1] = cvtpk(raw[i][0].z, raw[i][0].w);
            pk[2] = cvtpk(raw[i][1].x, raw[i][1].y);
            pk[3] = cvtpk(raw[i][1].z, raw[i][1].w);
            af[i] = *(bf16x8*)&pk;
            if constexpr (DUMPA) {
                if (wv == 0 && arow[i] < M)
                    *(u32x4*)(Adump + (size_t)k + aoff[i]) = pk;
            }
        }
    };
    auto mm = [&](bf16x8 (&af)[4], bf16x8 (&bf)[4]) {
        #pragma unroll
        for (int i = 0; i < 4; i++)
            #pragma unroll
            for (int j = 0; j < 4; j++)
                acc[i][j] = __builtin_amdgcn_mfma_f32_16x16x32_bf16(af[i], bf[j], acc[i][j], 0, 0, 0);
    };

    if constexpr (!AF32) {
        loadA16(a0, kBeg); loadB(b0, kBeg);
        int t = 0;
        for (; t + 2 <= nsteps; t += 2) {
            int k1 = kBeg + (t + 1) * 32;
            loadA16(a1, k1); loadB(b1, k1);
            mm(a0, b0);
            int k2 = kBeg + (t + 2) * 32;
            if (t + 2 >= nsteps) k2 = kBeg + (nsteps - 1) * 32;  // clamp (harmless reload)
            loadA16(a0, k2); loadB(b0, k2);
            mm(a1, b1);
        }
        if (t < nsteps) mm(a0, b0);
    } else {
        loadA32(r0, kBeg); loadB(b0, kBeg);
        int t = 0;
        for (; t + 2 <= nsteps; t += 2) {
            int kc = kBeg + t * 32;
            int k1 = kc + 32;
            loadA32(r1, k1); loadB(b1, k1);
            cvtA(r0, a0, kc);
            mm(a0, b0);
            int k2 = kc + 64;
            if (t + 2 >= nsteps) k2 = kBeg + (nsteps - 1) * 32;
            loadA32(r0, k2); loadB(b0, k2);
            cvtA(r1, a1, k1);
            mm(a1, b1);
        }
        if (t < nsteps) { int kc = kBeg + t * 32; cvtA(r0, a0, kc); mm(a0, b0); }
    }

    float* Cbase = Cp + (size_t)s * M * NOUT;
    #pragma unroll
    for (int i = 0; i < 4; i++)
        #pragma unroll
        for (int j = 0; j < 4; j++)
            #pragma unroll
            for (int e = 0; e < 4; e++) {
                int row = m0 + i * 16 + lg * 4 + e;
                int col = wn + j * 16 + lr;
                if (row < M) Cbase[(size_t)row * NOUT + col] = acc[i][j][e];
            }
}

// ---------------------------------------------------------------------------
// Small-GEMM kernel (S1..S5): LDS-staged, unchanged from round 3.
// ---------------------------------------------------------------------------
template<int BN, int MINW, bool AF32, bool BF32, int BIAS, bool RELU, bool OUTBF>
__global__ __launch_bounds__(256, MINW) void gemm_k(
    const void* __restrict__ Ap, const void* __restrict__ Bp, void* __restrict__ Cp,
    const float* __restrict__ bias,
    int M, int N, int K, int lda, int ldb, int nRT, int nNT, int KCH)
{
    constexpr int BM = 64;
    constexpr int WN = BN / 4;
    constexpr int FI = 4;
    constexpr int FJ = WN / 16;
    constexpr int CPT = BN / 64;
    __shared__ u16 ldsA[2][BM * 32];
    __shared__ u16 ldsB[2][BN * 32];

    const int tid = threadIdx.x;
    int bid = blockIdx.x;
    const int rt = bid % nRT; bid /= nRT;
    const int nt = bid % nNT;
    const int s  = bid / nNT;
    const int m0 = rt * BM, n0 = nt * BN;
    const int kBeg = s * KCH;
    const int kEnd = (K < kBeg + KCH) ? K : (kBeg + KCH);
    const int nsteps = (kEnd - kBeg) >> 5;

    const int w = tid >> 6, l = tid & 63;
    const int wn = w * WN;
    const int lr = l & 15, lg = l >> 4;

    f32x4 acc[FI][FJ] = {};
    float aR[8], bR[8];

    auto aIssue = [&](int buf, int k0) {
        if constexpr (AF32) {
            const float* A = (const float*)Ap;
            int r = tid >> 2, q = tid & 3;
            int gm = m0 + r; gm = (gm < M) ? gm : (M - 1);
            const float4* src = (const float4*)(A + (size_t)gm * lda + k0 + q * 8);
            float4 v0 = src[0], v1 = src[1];
            aR[0]=v0.x; aR[1]=v0.y; aR[2]=v0.z; aR[3]=v0.w;
            aR[4]=v1.x; aR[5]=v1.y; aR[6]=v1.z; aR[7]=v1.w;
        } else {
            const u16* A = (const u16*)Ap;
            int r = tid >> 2, cs = tid & 3;
            int c = swzc(r, cs);
            int gm = m0 + r; gm = (gm < M) ? gm : (M - 1);
            gload_lds16(A + (size_t)gm * lda + k0 + c * 8, &ldsA[buf][tid * 8]);
        }
    };
    auto aCommit = [&](int buf) {
        if constexpr (AF32) {
            int r = tid >> 2, q = tid & 3;
            u16x8 pk;
            #pragma unroll
            for (int e = 0; e < 8; e++) pk[e] = f2bf(aR[e]);
            *(u16x8*)&ldsA[buf][r * 32 + swzc(r, q) * 8] = pk;
        }
    };
    auto bIssue = [&](int buf, int k0) {
        if constexpr (BF32) {
            const float* B = (const float*)Bp;
            int r = tid >> 2, q = tid & 3;
            int gn = n0 + r; gn = (gn < N) ? gn : (N - 1);
            const float4* src = (const float4*)(B + (size_t)gn * ldb + k0 + q * 8);
            float4 v0 = src[0], v1 = src[1];
            bR[0]=v0.x; bR[1]=v0.y; bR[2]=v0.z; bR[3]=v0.w;
            bR[4]=v1.x; bR[5]=v1.y; bR[6]=v1.z; bR[7]=v1.w;
        } else {
            const u16* B = (const u16*)Bp;
            #pragma unroll
            for (int u = 0; u < CPT; u++) {
                int slot = u * 256 + tid;
                int r = slot >> 2, cs = slot & 3;
                int c = swzc(r, cs);
                int gn = n0 + r; gn = (gn < N) ? gn : (N - 1);
                gload_lds16(B + (size_t)gn * ldb + k0 + c * 8, &ldsB[buf][slot * 8]);
            }
        }
    };
    auto bCommit = [&](int buf) {
        if constexpr (BF32) {
            int r = tid >> 2, q = tid & 3;
            u16x8 pk;
            #pragma unroll
            for (int e = 0; e < 8; e++) pk[e] = f2bf(bR[e]);
            *(u16x8*)&ldsB[buf][r * 32 + swzc(r, q) * 8] = pk;
        }
    };

    aIssue(0, kBeg); bIssue(0, kBeg);
    aCommit(0); bCommit(0);
    __syncthreads();

    for (int t = 0; t < nsteps; t++) {
        const int k = kBeg + t * 32;
        const int cur = t & 1, nxt = cur ^ 1;
        if (t + 1 < nsteps) { aIssue(nxt, k + 32); bIssue(nxt, k + 32); }

        bf16x8 af[FI], bfr[FJ];
        #pragma unroll
        for (int i = 0; i < FI; i++) {
            int r = i * 16 + lr;
            af[i] = *(const bf16x8*)&ldsA[cur][r * 32 + swzc(r, lg) * 8];
        }
        #pragma unroll
        for (int j = 0; j < FJ; j++) {
            int r = wn + j * 16 + lr;
            bfr[j] = *(const bf16x8*)&ldsB[cur][r * 32 + swzc(r, lg) * 8];
        }
        #pragma unroll
        for (int i = 0; i < FI; i++)
            #pragma unroll
            for (int j = 0; j < FJ; j++)
                acc[i][j] = __builtin_amdgcn_mfma_f32_16x16x32_bf16(af[i], bfr[j], acc[i][j], 0, 0, 0);

        if (t + 1 < nsteps) { aCommit(nxt); bCommit(nxt); }
        __syncthreads();
    }

    #pragma unroll
    for (int i = 0; i < FI; i++)
        #pragma unroll
        for (int j = 0; j < FJ; j++)
            #pragma unroll
            for (int e = 0; e < 4; e++) {
                int row = m0 + i * 16 + lg * 4 + e;
                int col = n0 + wn + j * 16 + lr;
                if (row < M && col < N) {
                    float v = acc[i][j][e];
                    if constexpr (BIAS == 1) v += bias[row];
                    if constexpr (BIAS == 2) v += bias[col];
                    if constexpr (RELU) v = fmaxf(v, 0.0f);
                    if constexpr (OUTBF) ((u16*)Cp)[(size_t)row * N + col] = f2bf(v);
                    else ((float*)Cp)[(size_t)s * M * N + (size_t)row * N + col] = v;
                }
            }
}

// fused: sum split-K partials + residual -> LayerNorm -> relu -> bf16 (+f32) out. D=256.
__global__ __launch_bounds__(256) void ln_k(
    const float* __restrict__ part, long pStride, int nPart,
    const float* __restrict__ resid, const float* __restrict__ gamma, const float* __restrict__ beta,
    u16* __restrict__ obf, float* __restrict__ of32, int M)
{
    const int w = threadIdx.x >> 6, l = threadIdx.x & 63;
    for (int row = blockIdx.x * 4 + w; row < M; row += gridDim.x * 4) {
        size_t base = (size_t)row * 256 + l * 4;
        float4 v = *(const float4*)(part + base);
        for (int s = 1; s < nPart; s++) {
            float4 u = *(const float4*)(part + (size_t)s * pStride + base);
            v.x += u.x; v.y += u.y; v.z += u.z; v.w += u.w;
        }
        float4 r = *(const float4*)(resid + base);
        v.x += r.x; v.y += r.y; v.z += r.z; v.w += r.w;
        float sum = v.x + v.y + v.z + v.w;
        float sq  = v.x*v.x + v.y*v.y + v.z*v.z + v.w*v.w;
        #pragma unroll
        for (int o = 32; o >= 1; o >>= 1) {
            sum += __shfl_xor(sum, o, 64);
            sq  += __shfl_xor(sq, o, 64);
        }
        float mu  = sum * (1.0f / 256.0f);
        float var = sq * (1.0f / 256.0f) - mu * mu;
        float sc  = rsqrtf(var + 1e-5f);
        int c = l * 4;
        float y0 = fmaxf((v.x - mu) * sc * gamma[c + 0] + beta[c + 0], 0.0f);
        float y1 = fmaxf((v.y - mu) * sc * gamma[c + 1] + beta[c + 1], 0.0f);
        float y2 = fmaxf((v.z - mu) * sc * gamma[c + 2] + beta[c + 2], 0.0f);
        float y3 = fmaxf((v.w - mu) * sc * gamma[c + 3] + beta[c + 3], 0.0f);
        u16x4 pk; pk[0] = f2bf(y0); pk[1] = f2bf(y1); pk[2] = f2bf(y2); pk[3] = f2bf(y3);
        *(u16x4*)(obf + base) = pk;
        if (of32) { float4 o4; o4.x = y0; o4.y = y1; o4.z = y2; o4.w = y3; *(float4*)(of32 + base) = o4; }
    }
}

// sum split-K partials -> f32 out + bf16 copy (embedding)
__global__ __launch_bounds__(256) void sum_k(
    const float* __restrict__ p, long pStride, int nPart,
    float* __restrict__ of, u16* __restrict__ ob, int total4)
{
    int i = blockIdx.x * 256 + threadIdx.x;
    if (i >= total4) return;
    size_t b = (size_t)i * 4;
    float4 v = *(const float4*)(p + b);
    for (int s = 1; s < nPart; s++) {
        float4 u = *(const float4*)(p + (size_t)s * pStride + b);
        v.x += u.x; v.y += u.y; v.z += u.z; v.w += u.w;
    }
    *(float4*)(of + b) = v;
    u16x4 pk; pk[0] = f2bf(v.x); pk[1] = f2bf(v.y); pk[2] = f2bf(v.z); pk[3] = f2bf(v.w);
    *(u16x4*)(ob + b) = pk;
}

// transpose + bf16-convert the 5 weight matrices.
__global__ __launch_bounds__(256) void prep_k(
    const float* __restrict__ s0, const float* __restrict__ s1, const float* __restrict__ s2,
    const float* __restrict__ s3, const float* __restrict__ s4,
    u16* __restrict__ d0, u16* __restrict__ d1, u16* __restrict__ d2,
    u16* __restrict__ d3, u16* __restrict__ d4)
{
    int i = blockIdx.x * 256 + threadIdx.x;
    if (i < 65536) {
        int o = i >> 8, ii = i & 255; d0[i] = f2bf(s0[(size_t)ii * 256 + o]);
    } else if (i < 131072) {
        int j = i - 65536; int o = j >> 8, ii = j & 255; d1[j] = f2bf(s1[(size_t)ii * 256 + o]);
    } else if (i < 163840) {
        int j = i - 131072; int o = j >> 8, ii = j & 255; d2[j] = f2bf(s2[(size_t)ii * 128 + o]);
    } else if (i < 180224) {
        int j = i - 163840; int o = j >> 7, ii = j & 127; d3[j] = f2bf(s3[(size_t)ii * 128 + o]);
    } else if (i < 196608) {
        int j = i - 180224; int o = j >> 7, ii = j & 127; d4[j] = f2bf(s4[(size_t)ii * 128 + o]);
    }
}

extern "C" void kernel_launch(void* const* d_in, const int* in_sizes, int n_in,
                              void* d_out, int out_size, void* d_ws, size_t ws_size,
                              hipStream_t stream)
{
    if (n_in < 16) return;
    const int NN = 12000, DD = 256, EE = 128;
    const float* x   = (const float*)d_in[0];
    const float* adj = (const float*)d_in[1];
    const float* W1  = (const float*)d_in[2];
    const float* b1  = (const float*)d_in[3];
    const float* g1  = (const float*)d_in[4];
    const float* be1 = (const float*)d_in[5];
    const float* W2  = (const float*)d_in[6];
    const float* b2  = (const float*)d_in[7];
    const float* g2  = (const float*)d_in[8];
    const float* be2 = (const float*)d_in[9];
    const float* W3  = (const float*)d_in[10];
    const float* b3  = (const float*)d_in[11];
    const float* Wp1 = (const float*)d_in[12];
    const float* bp1 = (const float*)d_in[13];
    const float* Wp2 = (const float*)d_in[14];
    const float* bp2 = (const float*)d_in[15];
    float* zOut   = (float*)d_out;
    float* embOut = zOut + (size_t)NN * EE;

    char* ws = (char*)d_ws;
    size_t off = 0;
    auto alloc = [&](size_t bytes) -> void* {
        off = (off + 255) & ~(size_t)255;
        void* p = ws + off; off += bytes; return p;
    };

    const size_t adjElems = (size_t)NN * NN;
    bool cacheAdj = ws_size >= adjElems * 2 + 100000000ULL;
    u16* adjb = cacheAdj ? (u16*)alloc(adjElems * 2) : nullptr;

    u16* xW1t   = (u16*)alloc((size_t)DD * NN * 2);
    u16* hW2t   = (u16*)alloc((size_t)DD * NN * 2);
    u16* h2W3t  = (u16*)alloc((size_t)EE * NN * 2);
    u16* hbf    = (u16*)alloc((size_t)NN * DD * 2);
    float* hf32 = (float*)alloc((size_t)NN * DD * 4);
    u16* h2bf   = (u16*)alloc((size_t)NN * DD * 2);
    u16* embbf  = (u16*)alloc((size_t)NN * EE * 2);
    u16* p1bf   = (u16*)alloc((size_t)NN * EE * 2);
    u16* W1t    = (u16*)alloc(65536 * 2);
    u16* W2t    = (u16*)alloc(65536 * 2);
    u16* W3t    = (u16*)alloc(32768 * 2);
    u16* Wp1t   = (u16*)alloc(16384 * 2);
    u16* Wp2t   = (u16*)alloc(16384 * 2);

    // part buffer: max(S=4 x NN x DD, S=8 x NN x EE) x 4B  (equal: 49.15 MB)
    float* part = (float*)alloc((size_t)4 * NN * DD * 4);
    const int KCH4 = 3008;   // 94 steps x3, 93 steps last  (S=4)
    const int KCH8 = 1504;   // 47 steps x7, 46 steps last  (S=8, P3)

    prep_k<<<768, 256, 0, stream>>>(W1, W2, W3, Wp1, Wp2, W1t, W2t, W3t, Wp1t, Wp2t);

    // S1: xW1t[256][12000] = W1t @ x^T + b1
    gemm_k<64, 3, false, true, 1, false, true><<<4 * 188, 256, 0, stream>>>(
        W1t, x, xW1t, b1, DD, NN, DD, DD, DD, 4, 188, DD);

    // P1: part[s] = adj @ xW1 (fp32 adj stream -> cvt_pk; wave0 dumps bf16 adj)
    if (cacheAdj)
        pstream_k<4, 2, true, true><<<188 * 4, 256, 0, stream>>>(
            adj, xW1t, part, adjb, NN, NN, NN, NN, 188, KCH4, 188 * 4 / 8);
    else
        pstream_k<4, 2, true, false><<<188 * 4, 256, 0, stream>>>(
            adj, xW1t, part, nullptr, NN, NN, NN, NN, 188, KCH4, 188 * 4 / 8);

    // E1: h = relu(LN(t1 + x)) -> hbf (bf16) + hf32 (residual)
    ln_k<<<750, 256, 0, stream>>>(part, (long)NN * DD, 4, x, g1, be1, hbf, hf32, NN);

    // S2: hW2t = W2t @ h^T + b2
    gemm_k<64, 4, false, false, 1, false, true><<<4 * 188, 256, 0, stream>>>(
        W2t, hbf, hW2t, b2, DD, NN, DD, DD, DD, 4, 188, DD);

    // P2: part[s] = adj @ hW2 (bf16 adj stream)
    if (cacheAdj)
        pstream_k<4, 3, false, false><<<188 * 4, 256, 0, stream>>>(
            adjb, hW2t, part, nullptr, NN, NN, NN, NN, 188, KCH4, 188 * 4 / 8);
    else
        pstream_k<4, 2, true, false><<<188 * 4, 256, 0, stream>>>(
            adj, hW2t, part, nullptr, NN, NN, NN, NN, 188, KCH4, 188 * 4 / 8);

    // E2: h2 = relu(LN(t2 + h))
    ln_k<<<750, 256, 0, stream>>>(part, (long)NN * DD, 4, hf32, g2, be2, h2bf, nullptr, NN);

    // S3: h2W3t[128][12000] = W3t @ h2^T + b3
    gemm_k<64, 4, false, false, 1, false, true><<<2 * 188, 256, 0, stream>>>(
        W3t, h2bf, h2W3t, b3, EE, NN, DD, DD, DD, 2, 188, DD);

    // P3: part[s] = adj @ h2W3 (S=8 split-K for wave count; 2-wave blocks)
    if (cacheAdj)
        pstream_k<2, 3, false, false><<<188 * 8, 128, 0, stream>>>(
            adjb, h2W3t, part, nullptr, NN, NN, NN, NN, 188, KCH8, 188 * 8 / 8);
    else
        pstream_k<2, 2, true, false><<<188 * 8, 128, 0, stream>>>(
            adj, h2W3t, part, nullptr, NN, NN, NN, NN, 188, KCH8, 188 * 8 / 8);

    // E3: embedding out (fp32) + bf16 copy for proj head
    sum_k<<<1500, 256, 0, stream>>>(part, (long)NN * EE, 8, embOut, embbf, NN * EE / 4);

    // S4: p1 = relu(emb @ Wp1 + bp1)
    gemm_k<128, 4, false, false, 2, true, true><<<188, 256, 0, stream>>>(
        embbf, Wp1t, p1bf, bp1, NN, EE, EE, EE, EE, 188, 1, EE);

    // S5: z = p1 @ Wp2 + bp2 -> d_out (fp32)
    gemm_k<128, 4, false, false, 2, false, false><<<188, 256, 0, stream>>>(
        p1bf, Wp2t, zOut, bp2, NN, EE, EE, EE, EE, 188, 1, EE);
}